// Round 1
// baseline (228.733 us; speedup 1.0000x reference)
//
#include <hip/hip_runtime.h>
#include <math.h>

#define NB    2048
#define NS    200
#define ND    128
#define NH1   64
#define NH2   32
#define SB    32
#define NCH   7     // ceil(200/32)

// LDS layout (float offsets)
#define OFF_W1EFF 0                    // 128*64 = 8192
#define OFF_W2    8192                 // 64*32  = 2048
#define OFF_Q     10240                // 128
#define OFF_BIAS  10368                // 64
#define OFF_B2    10432                // 32
#define OFF_W3    10464                // 32
#define OFF_SC    10496                // 256 raw scores
#define OFF_WB    10752                // 256 softmax weights
#define OFF_BP    11008                // 4*65 = 260 bias partials
#define OFF_WRED  11272                // 8 wave-reduce scratch
#define OFF_UNION 11280                // 4608 floats union: kT[128][36]
#define OFF_H1    OFF_UNION            // 32*65 = 2080 (after GEMM1 done with kT)
#define OFF_PART  (OFF_UNION + 2080)   // 8*33 = 264
#define OFF_RED   (OFF_UNION + 2080 + 264) // 2*128 = 256
#define LDS_FLOATS (OFF_UNION + 4608)  // 15888 floats = 63552 B (< 64 KB)

extern "C" __global__ void __launch_bounds__(256, 2)
tdra_main(const float* __restrict__ query,
          const float* __restrict__ keys,
          const int*   __restrict__ kmask,
          const float* __restrict__ W1,
          const float* __restrict__ b1,
          const float* __restrict__ a1p,
          const float* __restrict__ W2,
          const float* __restrict__ b2,
          const float* __restrict__ a2p,
          const float* __restrict__ W3,
          const float* __restrict__ b3p,
          float* __restrict__ out)
{
    __shared__ float lds[LDS_FLOATS];
    const int tid = threadIdx.x;
    const int b   = blockIdx.x;

    const float a1 = a1p[0];
    const float a2 = a2p[0];
    const float b3 = b3p[0];

    // ---------- Phase 0a: stage q, W2, b2, W3 ----------
    if (tid < 32) {
        float4 qv = *(const float4*)(query + (size_t)b * ND + tid * 4);
        *(float4*)(lds + OFF_Q + tid * 4) = qv;
    }
    {
        float4 v0 = *(const float4*)(W2 + tid * 4);
        float4 v1 = *(const float4*)(W2 + 1024 + tid * 4);
        *(float4*)(lds + OFF_W2 + tid * 4) = v0;
        *(float4*)(lds + OFF_W2 + 1024 + tid * 4) = v1;
    }
    if (tid >= 64 && tid < 96)  lds[OFF_B2 + (tid - 64)] = b2[tid - 64];
    if (tid >= 96 && tid < 128) lds[OFF_W3 + (tid - 96)] = W3[tid - 96];
    __syncthreads();

    // ---------- Phase 0b: W1eff = W1a + W1d + q*W1c ; bias partials ----------
    #pragma unroll
    for (int i = 0; i < 8; ++i) {
        int e = i * 1024 + tid * 4;        // 0..8191, 4 at a time, same d per quad
        int d = e >> 6;
        float qd = lds[OFF_Q + d];
        float4 va = *(const float4*)(W1 + e);            // rows 0..127   (keys part)
        float4 vc = *(const float4*)(W1 + 16384 + e);    // rows 256..383 (k*q part)
        float4 vd = *(const float4*)(W1 + 24576 + e);    // rows 384..511 (k-q part)
        float4 r;
        r.x = va.x + vd.x + qd * vc.x;
        r.y = va.y + vd.y + qd * vc.y;
        r.z = va.z + vd.z + qd * vc.z;
        r.w = va.w + vd.w + qd * vc.w;
        *(float4*)(lds + OFF_W1EFF + e) = r;
    }
    {
        // bias_eff partials: q @ (W1b - W1d)
        int h = tid & 63, qt = tid >> 6;   // 4 quarters of 32 d each
        const float* pb = W1 + (size_t)(128 + qt * 32) * 64 + h;
        const float* pd = W1 + (size_t)(384 + qt * 32) * 64 + h;
        float p = 0.f;
        #pragma unroll 8
        for (int i = 0; i < 32; ++i)
            p = fmaf(lds[OFF_Q + qt * 32 + i], pb[i * 64] - pd[i * 64], p);
        lds[OFF_BP + qt * 65 + h] = p;
    }
    __syncthreads();
    if (tid < 64) {
        lds[OFF_BIAS + tid] = b1[tid] + lds[OFF_BP + tid] + lds[OFF_BP + 65 + tid]
                            + lds[OFF_BP + 130 + tid] + lds[OFF_BP + 195 + tid];
    }
    __syncthreads();

    const int tx = tid & 15;     // h-quad: h = 4*tx..4*tx+3
    const int ty = tid >> 4;     // s-pair: s = 2*ty, 2*ty+1
    const int s2 = tid & 31;     // GEMM2 s
    const int g2 = tid >> 5;     // GEMM2 j-quad 0..7

    // ---------- Main loop over 7 chunks of 32 s ----------
    for (int c = 0; c < NCH; ++c) {
        const int sbase = c * SB;

        // stage keys chunk -> kT[d][s'] (transposed, XOR-swizzled pairs)
        #pragma unroll
        for (int it = 0; it < 4; ++it) {
            int flat = it * 1024 + tid * 4;      // 4096 floats per chunk
            int d = flat & 127;
            int s = flat >> 7;                   // 0..31
            int gs = sbase + s;
            float4 kv = make_float4(0.f, 0.f, 0.f, 0.f);
            if (gs < NS)
                kv = *(const float4*)(keys + ((size_t)b * NS + gs) * ND + d);
            int col = 2 * ((s >> 1) ^ ((d >> 2) & 15)) + (s & 1);
            float* kt = lds + OFF_UNION;
            kt[(d + 0) * 36 + col] = kv.x;
            kt[(d + 1) * 36 + col] = kv.y;
            kt[(d + 2) * 36 + col] = kv.z;
            kt[(d + 3) * 36 + col] = kv.w;
        }
        __syncthreads();

        // GEMM1: acc[2s][4h] over d=0..127
        float a0x = 0.f, a0y = 0.f, a0z = 0.f, a0w = 0.f;
        float a1x = 0.f, a1y = 0.f, a1z = 0.f, a1w = 0.f;
        #pragma unroll 8
        for (int d = 0; d < 128; ++d) {
            float2 kv = *(const float2*)(lds + OFF_UNION + d * 36
                                         + 2 * (ty ^ ((d >> 2) & 15)));
            float4 wv = *(const float4*)(lds + OFF_W1EFF + d * 64 + 4 * tx);
            a0x = fmaf(kv.x, wv.x, a0x); a0y = fmaf(kv.x, wv.y, a0y);
            a0z = fmaf(kv.x, wv.z, a0z); a0w = fmaf(kv.x, wv.w, a0w);
            a1x = fmaf(kv.y, wv.x, a1x); a1y = fmaf(kv.y, wv.y, a1y);
            a1z = fmaf(kv.y, wv.z, a1z); a1w = fmaf(kv.y, wv.w, a1w);
        }
        // bias + PReLU (in regs, before overwriting kT region)
        float4 bv = *(const float4*)(lds + OFF_BIAS + 4 * tx);
        float h0[4], h1v[4];
        {
            float v;
            v = a0x + bv.x; h0[0] = fmaxf(v, 0.f) + a1 * fminf(v, 0.f);
            v = a0y + bv.y; h0[1] = fmaxf(v, 0.f) + a1 * fminf(v, 0.f);
            v = a0z + bv.z; h0[2] = fmaxf(v, 0.f) + a1 * fminf(v, 0.f);
            v = a0w + bv.w; h0[3] = fmaxf(v, 0.f) + a1 * fminf(v, 0.f);
            v = a1x + bv.x; h1v[0] = fmaxf(v, 0.f) + a1 * fminf(v, 0.f);
            v = a1y + bv.y; h1v[1] = fmaxf(v, 0.f) + a1 * fminf(v, 0.f);
            v = a1z + bv.z; h1v[2] = fmaxf(v, 0.f) + a1 * fminf(v, 0.f);
            v = a1w + bv.w; h1v[3] = fmaxf(v, 0.f) + a1 * fminf(v, 0.f);
        }
        __syncthreads();   // everyone done reading kT -> reuse region as h1L

        #pragma unroll
        for (int j = 0; j < 4; ++j) {
            lds[OFF_H1 + (2 * ty + 0) * 65 + 4 * tx + j] = h0[j];
            lds[OFF_H1 + (2 * ty + 1) * 65 + 4 * tx + j] = h1v[j];
        }
        __syncthreads();

        // GEMM2: h2[4] for (s2, j=4*g2..4*g2+3), then PReLU + dot W3
        float hacc0 = lds[OFF_B2 + 4 * g2 + 0];
        float hacc1 = lds[OFF_B2 + 4 * g2 + 1];
        float hacc2 = lds[OFF_B2 + 4 * g2 + 2];
        float hacc3 = lds[OFF_B2 + 4 * g2 + 3];
        #pragma unroll 8
        for (int h = 0; h < 64; ++h) {
            float hv = lds[OFF_H1 + s2 * 65 + h];
            float4 w2v = *(const float4*)(lds + OFF_W2 + h * 32 + 4 * g2);
            hacc0 = fmaf(hv, w2v.x, hacc0);
            hacc1 = fmaf(hv, w2v.y, hacc1);
            hacc2 = fmaf(hv, w2v.z, hacc2);
            hacc3 = fmaf(hv, w2v.w, hacc3);
        }
        {
            float part = 0.f, v;
            v = hacc0; v = fmaxf(v, 0.f) + a2 * fminf(v, 0.f); part = fmaf(v, lds[OFF_W3 + 4 * g2 + 0], part);
            v = hacc1; v = fmaxf(v, 0.f) + a2 * fminf(v, 0.f); part = fmaf(v, lds[OFF_W3 + 4 * g2 + 1], part);
            v = hacc2; v = fmaxf(v, 0.f) + a2 * fminf(v, 0.f); part = fmaf(v, lds[OFF_W3 + 4 * g2 + 2], part);
            v = hacc3; v = fmaxf(v, 0.f) + a2 * fminf(v, 0.f); part = fmaf(v, lds[OFF_W3 + 4 * g2 + 3], part);
            lds[OFF_PART + g2 * 33 + s2] = part;
        }
        __syncthreads();
        if (tid < SB) {
            float sc = b3;
            #pragma unroll
            for (int g = 0; g < 8; ++g) sc += lds[OFF_PART + g * 33 + tid];
            lds[OFF_SC + sbase + tid] = sc;
        }
        __syncthreads();
    }

    // ---------- time decay + mask + softmax ----------
    float sc = -INFINITY;
    if (tid < NS) {
        if (kmask[(size_t)b * NS + tid] != 0)
            sc = lds[OFF_SC + tid] * expf(0.1f * (float)(tid - (NS - 1)));
    }
    float m = sc;
    #pragma unroll
    for (int o = 32; o > 0; o >>= 1) m = fmaxf(m, __shfl_xor(m, o, 64));
    const int wid = tid >> 6, lane = tid & 63;
    if (lane == 0) lds[OFF_WRED + wid] = m;
    __syncthreads();
    float M = fmaxf(fmaxf(lds[OFF_WRED + 0], lds[OFF_WRED + 1]),
                    fmaxf(lds[OFF_WRED + 2], lds[OFF_WRED + 3]));
    float e = 0.f;
    if (tid < NS && M > -INFINITY) e = expf(sc - M);   // sc=-inf -> e=0
    float ssum = e;
    #pragma unroll
    for (int o = 32; o > 0; o >>= 1) ssum += __shfl_xor(ssum, o, 64);
    if (lane == 0) lds[OFF_WRED + 4 + wid] = ssum;
    __syncthreads();
    float SUM = lds[OFF_WRED + 4] + lds[OFF_WRED + 5]
              + lds[OFF_WRED + 6] + lds[OFF_WRED + 7];
    float wv = (SUM > 0.f) ? (e / SUM) : 0.f;
    if (tid < NS) {
        lds[OFF_WB + tid] = wv;
        out[(size_t)NB * ND + (size_t)b * NS + tid] = wv;
    }
    __syncthreads();

    // ---------- pass 2: weighted_sum = w @ keys ----------
    {
        const int d = tid & 127, half = tid >> 7;
        const float* kp = keys + ((size_t)b * NS + half * 100) * ND + d;
        float acc = 0.f;
        #pragma unroll 5
        for (int i = 0; i < 100; ++i)
            acc = fmaf(lds[OFF_WB + half * 100 + i], kp[(size_t)i * ND], acc);
        lds[OFF_RED + half * 128 + d] = acc;
    }
    __syncthreads();
    if (tid < 128)
        out[(size_t)b * ND + tid] = lds[OFF_RED + tid] + lds[OFF_RED + 128 + tid];
}

extern "C" void kernel_launch(void* const* d_in, const int* in_sizes, int n_in,
                              void* d_out, int out_size, void* d_ws, size_t ws_size,
                              hipStream_t stream) {
    (void)in_sizes; (void)n_in; (void)d_ws; (void)ws_size; (void)out_size;
    const float* query = (const float*)d_in[0];
    const float* keys  = (const float*)d_in[1];
    const int*   kmask = (const int*)d_in[2];
    const float* W1 = (const float*)d_in[3];
    const float* b1 = (const float*)d_in[4];
    const float* a1 = (const float*)d_in[5];
    const float* W2 = (const float*)d_in[6];
    const float* b2 = (const float*)d_in[7];
    const float* a2 = (const float*)d_in[8];
    const float* W3 = (const float*)d_in[9];
    const float* b3 = (const float*)d_in[10];
    float* out = (float*)d_out;

    hipLaunchKernelGGL(tdra_main, dim3(NB), dim3(256), 0, stream,
                       query, keys, kmask, W1, b1, a1, W2, b2, a2, W3, b3, out);
}